// Round 3
// baseline (1504.016 us; speedup 1.0000x reference)
//
#include <hip/hip_runtime.h>
#include <cstdint>

typedef unsigned int u32;
typedef unsigned long long u64;

#define BATCH 8
#define H 1024
#define W 1024
#define HW (H*W)
#define NPIX (BATCH*HW)
#define KTOP 2048
#define NBIN 8192
#define SELCAP 4096
#define SENT 0xFFFFFFFFu
#define WORDS_PER_B (HW/64)
#define NWORDS (BATCH*WORDS_PER_B)

// ws layout (bytes); [0, OFF_SEL) is memset to 0 each launch
#define OFF_HIST1  0
#define OFF_HIST2  (256*1024)
#define OFF_MISC   (512*1024)
#define OFF_BITMAP (513*1024)
#define OFF_SEL    (513*1024 + 1024*1024)
#define OFF_RESP   (2*1024*1024)
#define WS_FAST_BYTES ((size_t)OFF_RESP + (size_t)NPIX * 8)

// ---------------- f64 dilated conv + relu at one pixel (bit-deterministic) ----------------
__device__ __forceinline__ double conv_resp_f64(
    const float* __restrict__ in, const float* __restrict__ wc,
    const float* __restrict__ wsw, int b, int y, int x)
{
  const float* base = in + (size_t)b * 3 * HW;
  const float* Sp = base;
  const float* Cp = base + HW;
  double resp = 0.0;
  const int dil[3] = {1, 4, 16};
  #pragma unroll
  for (int di = 0; di < 3; ++di) {
    int d = dil[di];
    double ac = 0.0, as = 0.0;
    #pragma unroll
    for (int ky = 0; ky < 3; ++ky) {
      int yy = y + (ky - 1) * d;
      bool yok = ((unsigned)yy < (unsigned)H);
      #pragma unroll
      for (int kx = 0; kx < 3; ++kx) {
        int xx = x + (kx - 1) * d;
        bool ok = yok && ((unsigned)xx < (unsigned)W);
        double a  = ok ? (double)Cp[yy * W + xx] : 0.0;
        double s2 = ok ? (double)Sp[yy * W + xx] : 0.0;
        ac = fma(a,  (double)wc[di * 9 + ky * 3 + kx], ac);
        as = fma(s2, (double)wsw[di * 9 + ky * 3 + kx], as);
      }
    }
    resp += ac;
    resp += as;
  }
  return resp > 0.0 ? resp : 0.0;
}

__device__ __forceinline__ u64 make_key(double val, int p) {
  u64 dbits = __double_as_longlong(val);
  return (dbits & ~0xFFFFFull) | (u64)((~(u32)p) & 0xFFFFFu);
}

// ---------------- kernel 1: elementwise outputs + f64 conv -> convr(f32) [+ dresp(f64)] ----
template<bool STORE>
__global__ __launch_bounds__(256) void fused_main(
    const float* __restrict__ in, const float* __restrict__ wc,
    const float* __restrict__ wsw, float* __restrict__ out0,
    float* __restrict__ convr, double* __restrict__ dresp)
{
  int gid = blockIdx.x * 256 + threadIdx.x;
  int b = gid >> 20;
  int p = gid & (HW - 1);
  int y = p >> 10;
  int x = p & (W - 1);

  const float* base = in + (size_t)b * 3 * HW;
  float sv = base[p];
  float cv = base[HW + p];
  float rv = base[2 * HW + p];
  float* ob = out0 + (size_t)b * 3 * HW;
  ob[p] = sv;
  ob[HW + p] = cv;
  ob[2 * HW + p] = expf(rv) - 1.0f;

  double r = conv_resp_f64(in, wc, wsw, b, y, x);
  convr[(size_t)b * HW + p] = (float)r;
  if (STORE) dresp[(size_t)b * HW + p] = r;
}

// ---------------- kernel 2: f64 peak detection -> bitmap + level-1 histogram ----------------
template<bool USE_RESP>
__global__ __launch_bounds__(256) void peak_kernel(
    const float* __restrict__ in, const float* __restrict__ wc,
    const float* __restrict__ wsw, const double* __restrict__ dresp,
    u64* __restrict__ bitmap, u32* __restrict__ hist1)
{
  int gid = blockIdx.x * 256 + threadIdx.x;
  int b = gid >> 20;
  int p = gid & (HW - 1);
  int y = p >> 10;
  int x = p & (W - 1);
  if (y < 5 || y >= H - 5 || x < 5 || x >= W - 5) return;

  double c[5][5];
  if (USE_RESP) {
    const double* dr = dresp + (size_t)b * HW;
    #pragma unroll
    for (int i = 0; i < 5; ++i)
      #pragma unroll
      for (int j = 0; j < 5; ++j)
        c[i][j] = dr[(y + i - 2) * W + (x + j - 2)];
  } else {
    #pragma unroll
    for (int i = 0; i < 5; ++i)
      #pragma unroll
      for (int j = 0; j < 5; ++j)
        c[i][j] = conv_resp_f64(in, wc, wsw, b, y + i - 2, x + j - 2);
  }

  double rs[5][3];
  #pragma unroll
  for (int i = 0; i < 5; ++i)
    #pragma unroll
    for (int j = 0; j < 3; ++j)
      rs[i][j] = c[i][j] + c[i][j + 1] + c[i][j + 2];

  double s[3][3];
  #pragma unroll
  for (int i = 0; i < 3; ++i)
    #pragma unroll
    for (int j = 0; j < 3; ++j)
      s[i][j] = (rs[i][j] + rs[i + 1][j] + rs[i + 2][j]) * (1.0 / 9.0);

  double sc = s[1][1];
  if (!(sc > 0.1)) return;
  bool pk = true;
  #pragma unroll
  for (int i = 0; i < 3; ++i)
    #pragma unroll
    for (int j = 0; j < 3; ++j)
      if (!(i == 1 && j == 1)) pk = pk && (sc >= s[i][j]);
  if (!pk) return;

  double val = c[2][2];
  if (!(val > 0.1)) return;

  atomicOr(&bitmap[(size_t)b * WORDS_PER_B + (p >> 6)], 1ull << (p & 63));
  u64 k64 = make_key(val, p);
  atomicAdd(&hist1[b * NBIN + (u32)((k64 >> 51) & 0x1FFF)], 1u);
}

// ---------------- kernel 3/5: parallel suffix scan of 8192-bin histogram ----------------
__global__ __launch_bounds__(1024) void scan_kernel(
    const u32* __restrict__ hist, u32* __restrict__ t1a, u32* __restrict__ above_a,
    u32* __restrict__ thresh, int level)
{
  __shared__ u32 sfx[NBIN];
  int b = blockIdx.x;
  int tid = threadIdx.x;
  if (level == 2 && t1a[b] == SENT) return;

  const u32* h = hist + b * NBIN;
  #pragma unroll
  for (int k = 0; k < 8; ++k) sfx[tid * 8 + k] = h[tid * 8 + k];
  __syncthreads();

  for (int off = 1; off < NBIN; off <<= 1) {
    u32 t[8];
    #pragma unroll
    for (int k = 0; k < 8; ++k) {
      int i = tid * 8 + k;
      t[k] = (i + off < NBIN) ? sfx[i + off] : 0u;
    }
    __syncthreads();
    #pragma unroll
    for (int k = 0; k < 8; ++k) sfx[tid * 8 + k] += t[k];
    __syncthreads();
  }

  if (level == 1) {
    u32 total = sfx[0];
    if (total <= KTOP) {
      if (tid == 0) { t1a[b] = SENT; thresh[b] = 0u; }
      return;
    }
    #pragma unroll
    for (int k = 0; k < 8; ++k) {
      int i = tid * 8 + k;
      u32 s = sfx[i];
      u32 nxt = (i + 1 < NBIN) ? sfx[i + 1] : 0u;
      if (s >= KTOP && nxt < KTOP) { t1a[b] = (u32)i; above_a[b] = nxt; }
    }
  } else {
    u32 ab = above_a[b];
    u32 t1 = t1a[b];
    #pragma unroll
    for (int k = 0; k < 8; ++k) {
      int i = tid * 8 + k;
      u32 s = ab + sfx[i];
      u32 nxt = ab + ((i + 1 < NBIN) ? sfx[i + 1] : 0u);
      if (s >= KTOP && nxt < KTOP) thresh[b] = (t1 << 13) | (u32)i;
    }
  }
}

// ---------------- kernel 4: level-2 histogram over bitmap peaks ----------------
__global__ __launch_bounds__(256) void hist2_build(
    const float* __restrict__ in, const float* __restrict__ wc,
    const float* __restrict__ wsw, const u64* __restrict__ bitmap,
    const u32* __restrict__ t1a, u32* __restrict__ hist2)
{
  int w = blockIdx.x * 256 + threadIdx.x;
  if (w >= NWORDS) return;
  int b = w >> 14;
  u32 t1 = t1a[b];
  if (t1 == SENT) return;
  u64 m = bitmap[w];
  if (!m) return;
  int pbase = (w & (WORDS_PER_B - 1)) << 6;
  while (m) {
    int bit = __builtin_ctzll(m);
    m &= m - 1;
    int p = pbase + bit;
    double val = conv_resp_f64(in, wc, wsw, b, p >> 10, p & (W - 1));
    u64 k64 = make_key(val, p);
    if ((u32)((k64 >> 51) & 0x1FFF) == t1)
      atomicAdd(&hist2[b * NBIN + (u32)((k64 >> 38) & 0x1FFF)], 1u);
  }
}

// ---------------- kernel 6: compact candidates >= threshold ----------------
__global__ __launch_bounds__(256) void compact_kernel(
    const float* __restrict__ in, const float* __restrict__ wc,
    const float* __restrict__ wsw, const u64* __restrict__ bitmap,
    const u32* __restrict__ thresh, u64* __restrict__ sel, u32* __restrict__ selcnt)
{
  int w = blockIdx.x * 256 + threadIdx.x;
  if (w >= NWORDS) return;
  int b = w >> 14;
  u64 m = bitmap[w];
  if (!m) return;
  u32 th = thresh[b];
  int pbase = (w & (WORDS_PER_B - 1)) << 6;
  while (m) {
    int bit = __builtin_ctzll(m);
    m &= m - 1;
    int p = pbase + bit;
    double val = conv_resp_f64(in, wc, wsw, b, p >> 10, p & (W - 1));
    u64 k64 = make_key(val, p);
    if ((k64 >> 38) >= (u64)th) {
      u32 pos = atomicAdd(&selcnt[b], 1u);
      if (pos < SELCAP) sel[(size_t)b * SELCAP + pos] = k64;
    }
  }
}

// ---------------- kernel 7: per-batch bitonic sort + emit center_pred ----------------
__global__ __launch_bounds__(1024) void sort_out_kernel(
    const u64* __restrict__ sel, const u32* __restrict__ selcnt,
    const float* __restrict__ convr, float* __restrict__ center)
{
  __shared__ u64 sk[SELCAP];
  int b = blockIdx.x;
  int M = (int)selcnt[b]; if (M > SELCAP) M = SELCAP;
  const u64* sb = sel + (size_t)b * SELCAP;
  for (int i = threadIdx.x; i < SELCAP; i += 1024) sk[i] = (i < M) ? sb[i] : 0ULL;

  for (int k = 2; k <= SELCAP; k <<= 1) {
    for (int j = k >> 1; j > 0; j >>= 1) {
      __syncthreads();
      for (int i = threadIdx.x; i < SELCAP; i += 1024) {
        int l = i ^ j;
        if (l > i) {
          u64 a = sk[i], bb = sk[l];
          bool up = ((i & k) == 0);
          bool sw = up ? (a < bb) : (a > bb);
          if (sw) { sk[i] = bb; sk[l] = a; }
        }
      }
    }
  }
  __syncthreads();

  for (int i = threadIdx.x; i < KTOP; i += 1024) {
    float* o = center + ((size_t)b * KTOP + i) * 5;
    if (i < M) {
      u64 key = sk[i];
      u32 p = (~(u32)key) & 0xFFFFFu;
      float v = convr[(size_t)b * HW + p];
      o[0] = 1.0f;
      o[1] = (float)(p & (W - 1));
      o[2] = (float)(p >> 10);
      o[3] = v;
      o[4] = v;
    } else {
      o[0] = 0.f; o[1] = 0.f; o[2] = 0.f; o[3] = 0.f; o[4] = 0.f;
    }
  }
}

extern "C" void kernel_launch(void* const* d_in, const int* in_sizes, int n_in,
                              void* d_out, int out_size, void* d_ws, size_t ws_size,
                              hipStream_t stream) {
  const float* in  = (const float*)d_in[0];
  const float* wc  = (const float*)d_in[1];
  const float* wsw = (const float*)d_in[2];

  float* out0   = (float*)d_out;                     // (8,3,1024,1024)
  float* center = out0 + (size_t)BATCH * 3 * HW;     // (8,2048,5)
  float* convr  = center + (size_t)BATCH * KTOP * 5; // (8,1,1024,1024)

  char* w = (char*)d_ws;
  u32* hist1  = (u32*)(w + OFF_HIST1);
  u32* hist2  = (u32*)(w + OFF_HIST2);
  u32* misc   = (u32*)(w + OFF_MISC);
  u32* selcnt = misc;
  u32* t1a    = misc + 8;
  u32* above  = misc + 16;
  u32* thresh = misc + 24;
  u64* bitmap = (u64*)(w + OFF_BITMAP);
  u64* sel    = (u64*)(w + OFF_SEL);
  double* dresp = (double*)(w + OFF_RESP);

  bool fast = (ws_size >= WS_FAST_BYTES);

  hipMemsetAsync(w, 0, OFF_SEL, stream);

  if (fast) {
    fused_main<true><<<NPIX / 256, 256, 0, stream>>>(in, wc, wsw, out0, convr, dresp);
    peak_kernel<true><<<NPIX / 256, 256, 0, stream>>>(in, wc, wsw, dresp, bitmap, hist1);
  } else {
    fused_main<false><<<NPIX / 256, 256, 0, stream>>>(in, wc, wsw, out0, convr, nullptr);
    peak_kernel<false><<<NPIX / 256, 256, 0, stream>>>(in, wc, wsw, nullptr, bitmap, hist1);
  }
  scan_kernel<<<BATCH, 1024, 0, stream>>>(hist1, t1a, above, thresh, 1);
  hist2_build<<<(NWORDS + 255) / 256, 256, 0, stream>>>(in, wc, wsw, bitmap, t1a, hist2);
  scan_kernel<<<BATCH, 1024, 0, stream>>>(hist2, t1a, above, thresh, 2);
  compact_kernel<<<(NWORDS + 255) / 256, 256, 0, stream>>>(in, wc, wsw, bitmap, thresh, sel, selcnt);
  sort_out_kernel<<<BATCH, 1024, 0, stream>>>(sel, selcnt, convr, center);
}

// Round 4
// 1194.236 us; speedup vs baseline: 1.2594x; 1.2594x over previous
//
#include <hip/hip_runtime.h>
#include <cstdint>

typedef unsigned int u32;
typedef unsigned long long u64;

#define BATCH 8
#define H 1024
#define W 1024
#define HW (H*W)
#define NPIX (BATCH*HW)
#define KTOP 2048
#define NBIN 8192
#define SELCAP 4096
#define SENT 0xFFFFFFFFu
#define WORDS_PER_B (HW/64)
#define NWORDS (BATCH*WORDS_PER_B)

// peak tile geometry
#define TX 32
#define TY 8
#define RX (TX+4)
#define RY (TY+4)

// ws layout (bytes); [0, OFF_SEL) is memset to 0 each launch
#define OFF_HIST1  0
#define OFF_HIST2  (256*1024)
#define OFF_MISC   (512*1024)
#define OFF_BITMAP (513*1024)
#define OFF_SEL    (513*1024 + 1024*1024)
#define OFF_RESP   (2*1024*1024)
#define WS_FAST_BYTES ((size_t)OFF_RESP + (size_t)NPIX * 8)

// ---------------- f64 dilated conv + relu at one pixel (bit-deterministic) ----------------
__device__ __forceinline__ double conv_resp_f64(
    const float* __restrict__ in, const float* __restrict__ wc,
    const float* __restrict__ wsw, int b, int y, int x)
{
  const float* base = in + (size_t)b * 3 * HW;
  const float* Sp = base;
  const float* Cp = base + HW;
  double resp = 0.0;
  const int dil[3] = {1, 4, 16};
  #pragma unroll
  for (int di = 0; di < 3; ++di) {
    int d = dil[di];
    double ac = 0.0, as = 0.0;
    #pragma unroll
    for (int ky = 0; ky < 3; ++ky) {
      int yy = y + (ky - 1) * d;
      bool yok = ((unsigned)yy < (unsigned)H);
      #pragma unroll
      for (int kx = 0; kx < 3; ++kx) {
        int xx = x + (kx - 1) * d;
        bool ok = yok && ((unsigned)xx < (unsigned)W);
        double a  = ok ? (double)Cp[yy * W + xx] : 0.0;
        double s2 = ok ? (double)Sp[yy * W + xx] : 0.0;
        ac = fma(a,  (double)wc[di * 9 + ky * 3 + kx], ac);
        as = fma(s2, (double)wsw[di * 9 + ky * 3 + kx], as);
      }
    }
    resp += ac;
    resp += as;
  }
  return resp > 0.0 ? resp : 0.0;
}

__device__ __forceinline__ u64 make_key(double val, int p) {
  u64 dbits = __double_as_longlong(val);
  return (dbits & ~0xFFFFFull) | (u64)((~(u32)p) & 0xFFFFFu);
}

// ---------------- kernel 1: elementwise outputs + f64 conv -> convr(f32) [+ dresp(f64)] ----
template<bool STORE>
__global__ __launch_bounds__(256) void fused_main(
    const float* __restrict__ in, const float* __restrict__ wc,
    const float* __restrict__ wsw, float* __restrict__ out0,
    float* __restrict__ convr, double* __restrict__ dresp)
{
  int gid = blockIdx.x * 256 + threadIdx.x;
  int b = gid >> 20;
  int p = gid & (HW - 1);
  int y = p >> 10;
  int x = p & (W - 1);

  const float* base = in + (size_t)b * 3 * HW;
  float sv = base[p];
  float cv = base[HW + p];
  float rv = base[2 * HW + p];
  float* ob = out0 + (size_t)b * 3 * HW;
  ob[p] = sv;
  ob[HW + p] = cv;
  ob[2 * HW + p] = expf(rv) - 1.0f;

  double r = conv_resp_f64(in, wc, wsw, b, y, x);
  convr[(size_t)b * HW + p] = (float)r;
  if (STORE) dresp[(size_t)b * HW + p] = r;
}

// ---------------- kernel 2 (fast): LDS-tiled f64 peak detection ----------------
__global__ __launch_bounds__(256) void peak_tiled(
    const double* __restrict__ dresp, u64* __restrict__ bitmap, u32* __restrict__ hist1)
{
  __shared__ double t[RY][RX];
  int b = blockIdx.z;
  int tx0 = blockIdx.x * TX;
  int ty0 = blockIdx.y * TY;
  const double* dr = dresp + (size_t)b * HW;

  for (int idx = threadIdx.x; idx < RX * RY; idx += 256) {
    int r = idx / RX, cc = idx - r * RX;
    int gy = ty0 + r - 2;  gy = min(max(gy, 0), H - 1);
    int gx = tx0 + cc - 2; gx = min(max(gx, 0), W - 1);
    t[r][cc] = dr[gy * W + gx];
  }
  __syncthreads();

  int lx = threadIdx.x & (TX - 1);
  int ly = threadIdx.x >> 5;
  int x = tx0 + lx, y = ty0 + ly;
  if (y < 5 || y >= H - 5 || x < 5 || x >= W - 5) return;

  double cs0[5], cs1[5], cs2[5], val = 0.0;
  #pragma unroll
  for (int jc = 0; jc < 5; ++jc) {
    double v0 = t[ly + 0][lx + jc];
    double v1 = t[ly + 1][lx + jc];
    double v2 = t[ly + 2][lx + jc];
    double v3 = t[ly + 3][lx + jc];
    double v4 = t[ly + 4][lx + jc];
    cs0[jc] = v0 + v1 + v2;
    cs1[jc] = v1 + v2 + v3;
    cs2[jc] = v2 + v3 + v4;
    if (jc == 2) val = v2;
  }

  double sc = (cs1[1] + cs1[2] + cs1[3]) * (1.0 / 9.0);
  if (!(sc > 0.1)) return;

  bool pk = true;
  #pragma unroll
  for (int j = 0; j < 3; ++j) {
    pk = pk && (sc >= (cs0[j] + cs0[j + 1] + cs0[j + 2]) * (1.0 / 9.0));
    pk = pk && (sc >= (cs2[j] + cs2[j + 1] + cs2[j + 2]) * (1.0 / 9.0));
  }
  pk = pk && (sc >= (cs1[0] + cs1[1] + cs1[2]) * (1.0 / 9.0));
  pk = pk && (sc >= (cs1[2] + cs1[3] + cs1[4]) * (1.0 / 9.0));
  if (!pk) return;

  if (!(val > 0.1)) return;

  int p = y * W + x;
  atomicOr(&bitmap[(size_t)b * WORDS_PER_B + (p >> 6)], 1ull << (p & 63));
  u64 k64 = make_key(val, p);
  atomicAdd(&hist1[b * NBIN + (u32)((k64 >> 51) & 0x1FFF)], 1u);
}

// ---------------- kernel 2 (fallback): recompute conv per neighborhood ----------------
__global__ __launch_bounds__(256) void peak_slow(
    const float* __restrict__ in, const float* __restrict__ wc,
    const float* __restrict__ wsw, u64* __restrict__ bitmap, u32* __restrict__ hist1)
{
  int gid = blockIdx.x * 256 + threadIdx.x;
  int b = gid >> 20;
  int p = gid & (HW - 1);
  int y = p >> 10;
  int x = p & (W - 1);
  if (y < 5 || y >= H - 5 || x < 5 || x >= W - 5) return;

  double cs0[5], cs1[5], cs2[5], val = 0.0;
  #pragma unroll
  for (int jc = 0; jc < 5; ++jc) {
    double v0 = conv_resp_f64(in, wc, wsw, b, y - 2, x + jc - 2);
    double v1 = conv_resp_f64(in, wc, wsw, b, y - 1, x + jc - 2);
    double v2 = conv_resp_f64(in, wc, wsw, b, y,     x + jc - 2);
    double v3 = conv_resp_f64(in, wc, wsw, b, y + 1, x + jc - 2);
    double v4 = conv_resp_f64(in, wc, wsw, b, y + 2, x + jc - 2);
    cs0[jc] = v0 + v1 + v2;
    cs1[jc] = v1 + v2 + v3;
    cs2[jc] = v2 + v3 + v4;
    if (jc == 2) val = v2;
  }
  double sc = (cs1[1] + cs1[2] + cs1[3]) * (1.0 / 9.0);
  if (!(sc > 0.1)) return;
  bool pk = true;
  #pragma unroll
  for (int j = 0; j < 3; ++j) {
    pk = pk && (sc >= (cs0[j] + cs0[j + 1] + cs0[j + 2]) * (1.0 / 9.0));
    pk = pk && (sc >= (cs2[j] + cs2[j + 1] + cs2[j + 2]) * (1.0 / 9.0));
  }
  pk = pk && (sc >= (cs1[0] + cs1[1] + cs1[2]) * (1.0 / 9.0));
  pk = pk && (sc >= (cs1[2] + cs1[3] + cs1[4]) * (1.0 / 9.0));
  if (!pk) return;
  if (!(val > 0.1)) return;

  atomicOr(&bitmap[(size_t)b * WORDS_PER_B + (p >> 6)], 1ull << (p & 63));
  u64 k64 = make_key(val, p);
  atomicAdd(&hist1[b * NBIN + (u32)((k64 >> 51) & 0x1FFF)], 1u);
}

// ---------------- kernel 3/5: parallel suffix scan of 8192-bin histogram ----------------
__global__ __launch_bounds__(1024) void scan_kernel(
    const u32* __restrict__ hist, u32* __restrict__ t1a, u32* __restrict__ above_a,
    u32* __restrict__ thresh, int level)
{
  __shared__ u32 sfx[NBIN];
  int b = blockIdx.x;
  int tid = threadIdx.x;
  if (level == 2 && t1a[b] == SENT) return;

  const u32* h = hist + b * NBIN;
  #pragma unroll
  for (int k = 0; k < 8; ++k) sfx[tid * 8 + k] = h[tid * 8 + k];
  __syncthreads();

  for (int off = 1; off < NBIN; off <<= 1) {
    u32 t[8];
    #pragma unroll
    for (int k = 0; k < 8; ++k) {
      int i = tid * 8 + k;
      t[k] = (i + off < NBIN) ? sfx[i + off] : 0u;
    }
    __syncthreads();
    #pragma unroll
    for (int k = 0; k < 8; ++k) sfx[tid * 8 + k] += t[k];
    __syncthreads();
  }

  if (level == 1) {
    u32 total = sfx[0];
    if (total <= KTOP) {
      if (tid == 0) { t1a[b] = SENT; thresh[b] = 0u; }
      return;
    }
    #pragma unroll
    for (int k = 0; k < 8; ++k) {
      int i = tid * 8 + k;
      u32 s = sfx[i];
      u32 nxt = (i + 1 < NBIN) ? sfx[i + 1] : 0u;
      if (s >= KTOP && nxt < KTOP) { t1a[b] = (u32)i; above_a[b] = nxt; }
    }
  } else {
    u32 ab = above_a[b];
    u32 t1 = t1a[b];
    #pragma unroll
    for (int k = 0; k < 8; ++k) {
      int i = tid * 8 + k;
      u32 s = ab + sfx[i];
      u32 nxt = ab + ((i + 1 < NBIN) ? sfx[i + 1] : 0u);
      if (s >= KTOP && nxt < KTOP) thresh[b] = (t1 << 13) | (u32)i;
    }
  }
}

// ---------------- kernel 4: level-2 histogram over bitmap peaks ----------------
template<bool FAST>
__global__ __launch_bounds__(256) void hist2_build(
    const float* __restrict__ in, const float* __restrict__ wc,
    const float* __restrict__ wsw, const double* __restrict__ dresp,
    const u64* __restrict__ bitmap, const u32* __restrict__ t1a, u32* __restrict__ hist2)
{
  int w = blockIdx.x * 256 + threadIdx.x;
  if (w >= NWORDS) return;
  int b = w >> 14;
  u32 t1 = t1a[b];
  if (t1 == SENT) return;
  u64 m = bitmap[w];
  if (!m) return;
  int pbase = (w & (WORDS_PER_B - 1)) << 6;
  while (m) {
    int bit = __builtin_ctzll(m);
    m &= m - 1;
    int p = pbase + bit;
    double val = FAST ? dresp[(size_t)b * HW + p]
                      : conv_resp_f64(in, wc, wsw, b, p >> 10, p & (W - 1));
    u64 k64 = make_key(val, p);
    if ((u32)((k64 >> 51) & 0x1FFF) == t1)
      atomicAdd(&hist2[b * NBIN + (u32)((k64 >> 38) & 0x1FFF)], 1u);
  }
}

// ---------------- kernel 6: compact candidates >= threshold ----------------
template<bool FAST>
__global__ __launch_bounds__(256) void compact_kernel(
    const float* __restrict__ in, const float* __restrict__ wc,
    const float* __restrict__ wsw, const double* __restrict__ dresp,
    const u64* __restrict__ bitmap, const u32* __restrict__ thresh,
    u64* __restrict__ sel, u32* __restrict__ selcnt)
{
  int w = blockIdx.x * 256 + threadIdx.x;
  if (w >= NWORDS) return;
  int b = w >> 14;
  u64 m = bitmap[w];
  if (!m) return;
  u32 th = thresh[b];
  int pbase = (w & (WORDS_PER_B - 1)) << 6;
  while (m) {
    int bit = __builtin_ctzll(m);
    m &= m - 1;
    int p = pbase + bit;
    double val = FAST ? dresp[(size_t)b * HW + p]
                      : conv_resp_f64(in, wc, wsw, b, p >> 10, p & (W - 1));
    u64 k64 = make_key(val, p);
    if ((k64 >> 38) >= (u64)th) {
      u32 pos = atomicAdd(&selcnt[b], 1u);
      if (pos < SELCAP) sel[(size_t)b * SELCAP + pos] = k64;
    }
  }
}

// ---------------- kernel 7: per-batch bitonic sort + emit center_pred ----------------
__global__ __launch_bounds__(1024) void sort_out_kernel(
    const u64* __restrict__ sel, const u32* __restrict__ selcnt,
    const float* __restrict__ convr, float* __restrict__ center)
{
  __shared__ u64 sk[SELCAP];
  int b = blockIdx.x;
  int M = (int)selcnt[b]; if (M > SELCAP) M = SELCAP;
  const u64* sb = sel + (size_t)b * SELCAP;
  for (int i = threadIdx.x; i < SELCAP; i += 1024) sk[i] = (i < M) ? sb[i] : 0ULL;

  for (int k = 2; k <= SELCAP; k <<= 1) {
    for (int j = k >> 1; j > 0; j >>= 1) {
      __syncthreads();
      for (int i = threadIdx.x; i < SELCAP; i += 1024) {
        int l = i ^ j;
        if (l > i) {
          u64 a = sk[i], bb = sk[l];
          bool up = ((i & k) == 0);
          bool sw = up ? (a < bb) : (a > bb);
          if (sw) { sk[i] = bb; sk[l] = a; }
        }
      }
    }
  }
  __syncthreads();

  for (int i = threadIdx.x; i < KTOP; i += 1024) {
    float* o = center + ((size_t)b * KTOP + i) * 5;
    if (i < M) {
      u64 key = sk[i];
      u32 p = (~(u32)key) & 0xFFFFFu;
      float v = convr[(size_t)b * HW + p];
      o[0] = 1.0f;
      o[1] = (float)(p & (W - 1));
      o[2] = (float)(p >> 10);
      o[3] = v;
      o[4] = v;
    } else {
      o[0] = 0.f; o[1] = 0.f; o[2] = 0.f; o[3] = 0.f; o[4] = 0.f;
    }
  }
}

extern "C" void kernel_launch(void* const* d_in, const int* in_sizes, int n_in,
                              void* d_out, int out_size, void* d_ws, size_t ws_size,
                              hipStream_t stream) {
  const float* in  = (const float*)d_in[0];
  const float* wc  = (const float*)d_in[1];
  const float* wsw = (const float*)d_in[2];

  float* out0   = (float*)d_out;                     // (8,3,1024,1024)
  float* center = out0 + (size_t)BATCH * 3 * HW;     // (8,2048,5)
  float* convr  = center + (size_t)BATCH * KTOP * 5; // (8,1,1024,1024)

  char* w = (char*)d_ws;
  u32* hist1  = (u32*)(w + OFF_HIST1);
  u32* hist2  = (u32*)(w + OFF_HIST2);
  u32* misc   = (u32*)(w + OFF_MISC);
  u32* selcnt = misc;
  u32* t1a    = misc + 8;
  u32* above  = misc + 16;
  u32* thresh = misc + 24;
  u64* bitmap = (u64*)(w + OFF_BITMAP);
  u64* sel    = (u64*)(w + OFF_SEL);
  double* dresp = (double*)(w + OFF_RESP);

  bool fast = (ws_size >= WS_FAST_BYTES);

  hipMemsetAsync(w, 0, OFF_SEL, stream);

  if (fast) {
    fused_main<true><<<NPIX / 256, 256, 0, stream>>>(in, wc, wsw, out0, convr, dresp);
    peak_tiled<<<dim3(W / TX, H / TY, BATCH), 256, 0, stream>>>(dresp, bitmap, hist1);
    scan_kernel<<<BATCH, 1024, 0, stream>>>(hist1, t1a, above, thresh, 1);
    hist2_build<true><<<(NWORDS + 255) / 256, 256, 0, stream>>>(in, wc, wsw, dresp, bitmap, t1a, hist2);
    scan_kernel<<<BATCH, 1024, 0, stream>>>(hist2, t1a, above, thresh, 2);
    compact_kernel<true><<<(NWORDS + 255) / 256, 256, 0, stream>>>(in, wc, wsw, dresp, bitmap, thresh, sel, selcnt);
  } else {
    fused_main<false><<<NPIX / 256, 256, 0, stream>>>(in, wc, wsw, out0, convr, nullptr);
    peak_slow<<<NPIX / 256, 256, 0, stream>>>(in, wc, wsw, bitmap, hist1);
    scan_kernel<<<BATCH, 1024, 0, stream>>>(hist1, t1a, above, thresh, 1);
    hist2_build<false><<<(NWORDS + 255) / 256, 256, 0, stream>>>(in, wc, wsw, nullptr, bitmap, t1a, hist2);
    scan_kernel<<<BATCH, 1024, 0, stream>>>(hist2, t1a, above, thresh, 2);
    compact_kernel<false><<<(NWORDS + 255) / 256, 256, 0, stream>>>(in, wc, wsw, nullptr, bitmap, thresh, sel, selcnt);
  }
  sort_out_kernel<<<BATCH, 1024, 0, stream>>>(sel, selcnt, convr, center);
}